// Round 1
// baseline (434.596 us; speedup 1.0000x reference)
//
#include <hip/hip_runtime.h>
#include <stdint.h>
#include <math.h>

typedef float f4 __attribute__((ext_vector_type(4)));
typedef float f32x4 __attribute__((ext_vector_type(4)));
typedef short bf16x8 __attribute__((ext_vector_type(8)));
typedef unsigned short u16;
typedef unsigned short u16x4 __attribute__((ext_vector_type(4)));

#define NPIX 16384

// d_out offsets (floats). Return order: M1, M2, M1flat, M2flat, Ir_map, Vi_map, IrA, ViA
#define O_M1   0l
#define O_M2   16777216l
#define O_M1F  33554432l
#define O_M2F  50331648l
#define O_IR   67108864l
#define O_VI   71303168l
#define O_IRA  75497472l
#define O_VIA  75563008l
#define FLATD  33554432l   // offset from M to its flat duplicate (same for M1,M2)

// ws offsets (bytes)
#define WS_SUMP 0        // 8*32 floats
#define WS_MMXE 1024     // 16 uints (per tensor min/max encoded)
#define WS_MMXA 1088     // 2 uints (activation map min/max)
#define WS_MEAN 1152     // 8 floats
#define WS_MNT  1184     // 8 floats
#define WS_INV  1216     // 8 floats
#define WS_W1R  2048     // 73728 floats, w1 relaid as [ic][k9][oc]

struct EPtrs { const float* p[8]; };

__device__ __forceinline__ u16 f2bf(float x){
  unsigned u = __float_as_uint(x);
  unsigned r = (u + 0x7fffu + ((u >> 16) & 1u)) >> 16;   // RNE
  return (u16)r;
}
__device__ __forceinline__ float bf2f(u16 v){
  return __uint_as_float(((unsigned)v) << 16);
}
// monotone float<->uint map for deterministic atomic min/max
__device__ __forceinline__ unsigned fenc(float x){
  unsigned u = __float_as_uint(x);
  return (u & 0x80000000u) ? ~u : (u | 0x80000000u);
}
__device__ __forceinline__ float fdec(unsigned u){
  unsigned v = (u & 0x80000000u) ? (u & 0x7fffffffu) : ~u;
  return __uint_as_float(v);
}

// ---------------- init atomics ----------------
__global__ void k_init(unsigned* mmxe, unsigned* mmxa){
  int t = threadIdx.x;
  if (t < 8){ mmxe[2*t] = 0xFFFFFFFFu; mmxe[2*t+1] = 0u; }
  if (t == 8){ mmxa[0] = 0xFFFFFFFFu; mmxa[1] = 0u; }
}

// ---------------- weight re-layout: w1[oc][ic][k] -> w1r[ic][k][oc] ----------------
__global__ void k_prep(const float* __restrict__ w1, float* __restrict__ w1r){
  int i = blockIdx.x*256 + threadIdx.x;
  if (i < 73728){
    int ic = i / 576; int rem = i - ic*576; int k = rem >> 6; int oc = rem & 63;
    w1r[i] = w1[(oc*128 + ic)*9 + k];
  }
}

// ---------------- per-tensor stats + Gram partials (MFMA bf16) ----------------
// grid 256 = 8 tensors * 4 batch * 8 slices(2048 n each). block 256.
__global__ __launch_bounds__(256) void k_stats_gram(EPtrs eps,
    float* __restrict__ gram, float* __restrict__ sump, unsigned* __restrict__ mmxe){
  int bid = blockIdx.x;
  int t = bid >> 5; int rb = bid & 31; int b = rb >> 3; int s = rb & 7;
  const float* E = eps.p[t];
  __shared__ u16 lds[64*136];           // [c][n(128)+pad8] bf16
  __shared__ float red[768];
  int tid = threadIdx.x;
  int lane = tid & 63, wave = tid >> 6;
  f32x4 acc[4];
  #pragma unroll
  for (int i=0;i<4;++i) acc[i] = (f32x4){0.f,0.f,0.f,0.f};
  float vmin = 3.4e38f, vmax = -3.4e38f, vsum = 0.f;
  int rowS = tid >> 5;            // 0..7
  int colS = (tid & 31) * 4;      // 0..124
  int rA = wave*16 + (lane & 15);
  int kb = (lane >> 4) * 8;
  long nbase = (long)s * 2048;
  for (int ch = 0; ch < 16; ++ch){
    long n0 = nbase + ch*128;
    __syncthreads();
    #pragma unroll
    for (int p = 0; p < 8; ++p){
      int row = p*8 + rowS;
      f4 v = *(const f4*)&E[(long)(b*64 + row)*NPIX + n0 + colS];
      vsum += v[0]+v[1]+v[2]+v[3];
      vmin = fminf(vmin, fminf(fminf(v[0],v[1]), fminf(v[2],v[3])));
      vmax = fmaxf(vmax, fmaxf(fmaxf(v[0],v[1]), fmaxf(v[2],v[3])));
      u16x4 w; w[0]=f2bf(v[0]); w[1]=f2bf(v[1]); w[2]=f2bf(v[2]); w[3]=f2bf(v[3]);
      *(u16x4*)&lds[row*136 + colS] = w;
    }
    __syncthreads();
    #pragma unroll
    for (int ks = 0; ks < 4; ++ks){
      bf16x8 a = *(bf16x8*)&lds[rA*136 + ks*32 + kb];
      #pragma unroll
      for (int cb = 0; cb < 4; ++cb){
        bf16x8 bb = *(bf16x8*)&lds[(cb*16 + (lane&15))*136 + ks*32 + kb];
        acc[cb] = __builtin_amdgcn_mfma_f32_16x16x32_bf16(a, bb, acc[cb], 0, 0, 0);
      }
    }
  }
  // gram partial write: S[c][d], c = 16*wave + 4*(lane>>4)+rr, d = 16*cb + (lane&15)
  long gbase = ((long)((t*4 + b)*8 + s)) * 4096;
  #pragma unroll
  for (int cb = 0; cb < 4; ++cb){
    int d = cb*16 + (lane & 15);
    #pragma unroll
    for (int rr = 0; rr < 4; ++rr){
      int c = 16*wave + 4*(lane>>4) + rr;
      gram[gbase + c*64 + d] = acc[cb][rr];
    }
  }
  // stats reduce
  red[tid] = vsum; red[256+tid] = vmin; red[512+tid] = vmax;
  __syncthreads();
  for (int off = 128; off > 0; off >>= 1){
    if (tid < off){
      red[tid] += red[tid+off];
      red[256+tid] = fminf(red[256+tid], red[256+tid+off]);
      red[512+tid] = fmaxf(red[512+tid], red[512+tid+off]);
    }
    __syncthreads();
  }
  if (tid == 0){
    sump[t*32 + b*8 + s] = red[0];
    atomicMin(&mmxe[2*t], fenc(red[256]));
    atomicMax(&mmxe[2*t+1], fenc(red[512]));
  }
}

// ---------------- finalize per-tensor scalars ----------------
__global__ void k_finalize(const float* __restrict__ sump, const unsigned* __restrict__ mmxe,
                           float* __restrict__ meanA, float* __restrict__ mntA, float* __restrict__ invA){
  int t = threadIdx.x;
  if (t < 8){
    float s = 0.f;
    for (int j = 0; j < 32; ++j) s += sump[t*32 + j];
    float mean = s / 4194304.0f;
    float mn = fdec(mmxe[2*t]), mx = fdec(mmxe[2*t+1]);
    float mnt = fmaxf(mn - mean, 1e-10f);
    float mxt = fmaxf(mx - mean, 1e-10f);
    meanA[t] = mean; mntA[t] = mnt;
    invA[t] = 1.0f / (mxt - mnt + 1e-10f);
  }
}

// ---------------- softmax over axis=1 (rows c, per column d) ----------------
// grid 32 = (t,b). W[c][d] bf16 written to Wb.
__global__ void k_softmax(const float* __restrict__ gram, u16* __restrict__ Wb){
  int bid = blockIdx.x; int t = bid >> 2; int b = bid & 3;
  __shared__ float S[64*65];
  int tid = threadIdx.x;
  long gb = (long)(t*4 + b)*8*4096;
  for (int i = tid; i < 4096; i += 256){
    float v = 0.f;
    for (int s = 0; s < 8; ++s) v += gram[gb + s*4096 + i];
    S[(i>>6)*65 + (i&63)] = v;
  }
  __syncthreads();
  if (tid < 64){
    int d = tid;
    float mx = -3.4e38f;
    for (int c = 0; c < 64; ++c) mx = fmaxf(mx, S[c*65+d]);
    float sum = 0.f;
    for (int c = 0; c < 64; ++c){ float e = expf(S[c*65+d]-mx); S[c*65+d] = e; sum += e; }
    float inv = 1.0f/sum;
    long wb = (long)(t*4 + b)*4096;
    for (int c = 0; c < 64; ++c) Wb[wb + c*64 + d] = f2bf(S[c*65+d]*inv);
  }
}

// ---------------- conv1 3x3 (fp32 VALU) + bias + leaky ----------------
// grid 512 = (b,h). block 256: thread = 4 oc x 8 w.
__global__ __launch_bounds__(256) void k_conv1(const float* __restrict__ fc,
    const float* __restrict__ w1r, const float* __restrict__ b1, float* __restrict__ cat){
  int bid = blockIdx.x; int b = bid >> 7; int h = bid & 127;
  __shared__ float xin[16*3*132];   // [ic16][r3][col132], col = w+1 (halo)
  __shared__ float wch[16*9*64];    // [ic16][k9][oc64]
  int tid = threadIdx.x;
  int oc0 = (tid >> 4) * 4;
  int w0  = (tid & 15) * 8;
  float acc[4][8];
  #pragma unroll
  for (int o=0;o<4;++o)
    #pragma unroll
    for (int w=0;w<8;++w) acc[o][w] = 0.f;
  for (int icc = 0; icc < 8; ++icc){
    __syncthreads();
    for (int i = tid; i < 6336; i += 256){
      int ic = i / 396; int rem = i - ic*396; int r = rem / 132; int cl = rem - r*132;
      int w = cl - 1; int hr = h + r - 1;
      float v = 0.f;
      if ((unsigned)w < 128u && (unsigned)hr < 128u && cl < 130)
        v = fc[(long)((b*128 + icc*16 + ic)*128 + hr)*128 + w];
      xin[i] = v;
    }
    for (int i = tid; i < 9216; i += 256) wch[i] = w1r[icc*9216 + i];
    __syncthreads();
    for (int ic = 0; ic < 16; ++ic){
      float xr[3][10];
      #pragma unroll
      for (int r = 0; r < 3; ++r){
        const float* xp = &xin[ic*396 + r*132 + w0];
        f4 a0 = *(const f4*)xp; f4 a1 = *(const f4*)(xp+4);
        xr[r][0]=a0[0]; xr[r][1]=a0[1]; xr[r][2]=a0[2]; xr[r][3]=a0[3];
        xr[r][4]=a1[0]; xr[r][5]=a1[1]; xr[r][6]=a1[2]; xr[r][7]=a1[3];
        xr[r][8]=xp[8]; xr[r][9]=xp[9];
      }
      #pragma unroll
      for (int kh = 0; kh < 3; ++kh)
        #pragma unroll
        for (int kw = 0; kw < 3; ++kw){
          f4 wv = *(const f4*)&wch[ic*576 + (kh*3+kw)*64 + oc0];
          #pragma unroll
          for (int w = 0; w < 8; ++w){
            float x = xr[kh][w + kw];
            acc[0][w] = fmaf(wv[0], x, acc[0][w]);
            acc[1][w] = fmaf(wv[1], x, acc[1][w]);
            acc[2][w] = fmaf(wv[2], x, acc[2][w]);
            acc[3][w] = fmaf(wv[3], x, acc[3][w]);
          }
        }
    }
  }
  #pragma unroll
  for (int o = 0; o < 4; ++o){
    float bb = b1[oc0+o];
    f4 y0, y1;
    #pragma unroll
    for (int w = 0; w < 4; ++w){
      float v0 = acc[o][w] + bb;   y0[w] = v0 > 0.f ? v0 : 0.01f*v0;
      float v1 = acc[o][w+4] + bb; y1[w] = v1 > 0.f ? v1 : 0.01f*v1;
    }
    float* dst = &cat[(long)((b*64 + oc0+o)*128 + h)*128 + w0];
    *(f4*)dst = y0; *(f4*)(dst+4) = y1;
  }
}

// ---------------- conv2 3x3 (64ch -> 1) + bias, plus global min/max of result ----------------
// grid 512 = (b,h). block 256.
__global__ __launch_bounds__(256) void k_conv2(const float* __restrict__ cat,
    const float* __restrict__ w2, const float* __restrict__ b2p,
    float* __restrict__ am, unsigned* __restrict__ mmxa){
  int bid = blockIdx.x; int b = bid >> 7; int h = bid & 127;
  __shared__ u16 l2[64*3*132];
  __shared__ float w2l[576];
  __shared__ float red2[256];
  int tid = threadIdx.x;
  for (int i = tid; i < 576; i += 256) w2l[i] = w2[i];
  for (int i = tid; i < 25344; i += 256){
    int ic = i / 396; int rem = i - ic*396; int r = rem / 132; int cl = rem - r*132;
    int w = cl - 1; int hr = h + r - 1;
    float v = 0.f;
    if ((unsigned)w < 128u && (unsigned)hr < 128u && cl < 130)
      v = cat[(long)((b*64 + ic)*128 + hr)*128 + w];
    l2[i] = f2bf(v);
  }
  __syncthreads();
  int w = tid & 127, icg = tid >> 7;
  float a = 0.f;
  for (int ic = icg*32; ic < icg*32+32; ++ic){
    #pragma unroll
    for (int r = 0; r < 3; ++r)
      #pragma unroll
      for (int kw = 0; kw < 3; ++kw)
        a = fmaf(bf2f(l2[ic*396 + r*132 + (w + kw)]), w2l[ic*9 + r*3 + kw], a);
  }
  red2[tid] = a;
  __syncthreads();
  float av = 0.f;
  if (icg == 0){
    av = red2[w] + red2[128 + w] + b2p[0];
    am[(long)(b*128 + h)*128 + w] = av;
  }
  __syncthreads();
  red2[tid] = (icg == 0) ? av : -3.4e38f;
  __syncthreads();
  for (int off = 128; off > 0; off >>= 1){
    if (tid < off) red2[tid] = fmaxf(red2[tid], red2[tid+off]);
    __syncthreads();
  }
  if (tid == 0) atomicMax(&mmxa[1], fenc(red2[0]));
  __syncthreads();
  red2[tid] = (icg == 0) ? av : 3.4e38f;
  __syncthreads();
  for (int off = 128; off > 0; off >>= 1){
    if (tid < off) red2[tid] = fminf(red2[tid], red2[tid+off]);
    __syncthreads();
  }
  if (tid == 0) atomicMin(&mmxa[0], fenc(red2[0]));
}

// ---------------- Ir/Vi maps ----------------
__global__ void k_maps(const float* __restrict__ cat, const float* __restrict__ am,
                       const unsigned* __restrict__ mmxa, float* __restrict__ out){
  long e = ((long)blockIdx.x*256 + threadIdx.x) * 4;   // over 4,194,304 cat elems
  float mn = fdec(mmxa[0]);
  float inv = 1.0f / (fdec(mmxa[1]) - mn + 1e-10f);
  f4 c = *(const f4*)&cat[e];
  f4 a = *(const f4*)&am[(e >> 20)*16384 + (e & 16383)];
  f4 nam = (a - mn) * inv;
  f4 ir = nam * c;
  f4 vi = (1.0f - nam) * c;
  *(f4*)&out[O_IR + e] = ir;
  *(f4*)&out[O_VI + e] = vi;
}

// ---------------- fuse: fw = W*fr (MFMA) + norm-term + f, write M & flat copy ----------------
// grid 2048 = 8t * 4b * 64 ntile(256). block 256.
__global__ __launch_bounds__(256) void k_fuse(EPtrs eps, const u16* __restrict__ Wb,
    const float* __restrict__ meanA, const float* __restrict__ mntA, const float* __restrict__ invA,
    float* __restrict__ out){
  int bid = blockIdx.x;
  int t = bid >> 8; int rem = bid & 255; int b = rem >> 6; int nt = rem & 63;
  long n0 = (long)nt * 256;
  const float* E = eps.p[t];
  __shared__ u16 fr[64*260];     // [d][n(256)+pad4] bf16
  __shared__ u16 Wl[64*72];      // [c][d(64)+pad8] bf16
  int tid = threadIdx.x; int lane = tid & 63; int wave = tid >> 6;
  { long wb = (long)(t*4 + b)*4096;
    for (int i = tid; i < 4096; i += 256) Wl[(i>>6)*72 + (i&63)] = Wb[wb + i]; }
  #pragma unroll 4
  for (int i = 0; i < 16; ++i){
    int r = wave + 4*i;
    f4 v = *(const f4*)&E[(long)(b*64 + r)*NPIX + n0 + 4*lane];
    u16x4 u; u[0]=f2bf(v[0]); u[1]=f2bf(v[1]); u[2]=f2bf(v[2]); u[3]=f2bf(v[3]);
    *(u16x4*)&fr[r*260 + 4*lane] = u;
  }
  __syncthreads();
  f32x4 acc[16];
  #pragma unroll
  for (int i = 0; i < 16; ++i) acc[i] = (f32x4){0.f,0.f,0.f,0.f};
  int kb = (lane >> 4) * 8; int jc = lane & 15;
  #pragma unroll
  for (int ks = 0; ks < 2; ++ks){
    bf16x8 a = *(bf16x8*)&Wl[(wave*16 + jc)*72 + ks*32 + kb];
    #pragma unroll
    for (int j0 = 0; j0 < 16; ++j0){
      bf16x8 bv;
      #pragma unroll
      for (int e8 = 0; e8 < 8; ++e8)
        bv[e8] = (short)fr[(ks*32 + kb + e8)*260 + j0*16 + jc];
      acc[j0] = __builtin_amdgcn_mfma_f32_16x16x32_bf16(a, bv, acc[j0], 0, 0, 0);
    }
  }
  float mean = meanA[t], mnt = mntA[t], inv = invA[t];
  long Mbase = (t & 1) ? O_M2 : O_M1;
  long g = t >> 1;
  int rbase = wave*16 + (lane>>4)*4;
  #pragma unroll
  for (int j0 = 0; j0 < 16; ++j0){
    long n = n0 + j0*16 + jc;
    #pragma unroll
    for (int rr = 0; rr < 4; ++rr){
      int c = rbase + rr;
      float f = E[(long)(b*64 + c)*NPIX + n];
      float tv = fmaxf(f - mean, 1e-10f);
      float val = (tv - mnt)*inv + acc[j0][rr] + f;
      long dst = Mbase + ((long)(b*256 + g*64 + c))*NPIX + n;
      out[dst] = val;
      out[dst + FLATD] = val;
    }
  }
}

// ---------------- activation outputs (reads am in-place from ViA region) ----------------
__global__ void k_acts(const unsigned* __restrict__ mmxa, float* __restrict__ out){
  long e = ((long)blockIdx.x*256 + threadIdx.x) * 4;   // 65536 elems
  float mn = fdec(mmxa[0]);
  float inv = 1.0f / (fdec(mmxa[1]) - mn + 1e-10f);
  f4 a = *(const f4*)&out[O_VIA + e];
  f4 nam = (a - mn) * inv;
  *(f4*)&out[O_IRA + e] = nam;
  *(f4*)&out[O_VIA + e] = 1.0f - nam;
}

extern "C" void kernel_launch(void* const* d_in, const int* in_sizes, int n_in,
                              void* d_out, int out_size, void* d_ws, size_t ws_size,
                              hipStream_t stream){
  (void)in_sizes; (void)n_in; (void)out_size; (void)ws_size;
  EPtrs ep;
  for (int i = 0; i < 8; ++i) ep.p[i] = (const float*)d_in[i];
  const float* fc = (const float*)d_in[8];
  const float* w1 = (const float*)d_in[9];
  const float* b1 = (const float*)d_in[10];
  const float* w2 = (const float*)d_in[11];
  const float* b2 = (const float*)d_in[12];
  float* out = (float*)d_out;
  char* ws = (char*)d_ws;
  float* sump   = (float*)(ws + WS_SUMP);
  unsigned* mmxe = (unsigned*)(ws + WS_MMXE);
  unsigned* mmxa = (unsigned*)(ws + WS_MMXA);
  float* meanA  = (float*)(ws + WS_MEAN);
  float* mntA   = (float*)(ws + WS_MNT);
  float* invA   = (float*)(ws + WS_INV);
  float* w1r    = (float*)(ws + WS_W1R);
  // d_out-aliased scratch (each consumed before its real output is written):
  float* gram = out + O_M1F;            // consumed by k_softmax, overwritten by k_fuse
  float* cat  = out + O_M2F;            // consumed by k_conv2/k_maps, overwritten by k_fuse
  u16*   Wb   = (u16*)(out + O_IRA);    // consumed by k_fuse, overwritten by k_acts
  float* am   = out + O_VIA;            // consumed by k_maps/k_acts (in-place)

  k_init      <<<1,    64, 0, stream>>>(mmxe, mmxa);
  k_prep      <<<288, 256, 0, stream>>>(w1, w1r);
  k_stats_gram<<<256, 256, 0, stream>>>(ep, gram, sump, mmxe);
  k_finalize  <<<1,    64, 0, stream>>>(sump, mmxe, meanA, mntA, invA);
  k_softmax   <<<32,  256, 0, stream>>>(gram, Wb);
  k_conv1     <<<512, 256, 0, stream>>>(fc, w1r, b1, cat);
  k_conv2     <<<512, 256, 0, stream>>>(cat, w2, b2, am, mmxa);
  k_maps      <<<4096,256, 0, stream>>>(cat, am, mmxa, out);
  k_fuse      <<<2048,256, 0, stream>>>(ep, Wb, meanA, mntA, invA, out);
  k_acts      <<<64,  256, 0, stream>>>(mmxa, out);
}

// Round 2
// 289.437 us; speedup vs baseline: 1.5015x; 1.5015x over previous
//
#include <hip/hip_runtime.h>
#include <stdint.h>
#include <math.h>

typedef float f4 __attribute__((ext_vector_type(4)));
typedef float f32x4 __attribute__((ext_vector_type(4)));
typedef short bf16x8 __attribute__((ext_vector_type(8)));
typedef _Float16 f16x8 __attribute__((ext_vector_type(8)));
typedef unsigned short u16;
typedef unsigned short u16x4 __attribute__((ext_vector_type(4)));

#define NPIX 16384

// d_out offsets (floats). Return order: M1, M2, M1flat, M2flat, Ir_map, Vi_map, IrA, ViA
#define O_M1   0l
#define O_M2   16777216l
#define O_M1F  33554432l
#define O_M2F  50331648l
#define O_IR   67108864l
#define O_VI   71303168l
#define O_IRA  75497472l
#define O_VIA  75563008l
#define FLATD  33554432l   // offset from M to its flat duplicate (same for M1,M2)

// ws offsets (bytes)
#define WS_SUMP 0        // 8*32 floats
#define WS_MMXE 1024     // 16 uints (per tensor min/max encoded)
#define WS_MMXA 1088     // 2 uints (activation map min/max)
#define WS_MEAN 1152     // 8 floats
#define WS_MNT  1184     // 8 floats
#define WS_INV  1216     // 8 floats
#define WS_W1M  2048     // 73728 u16, w1 as f16 relaid [icc][k9][oc][ic]

struct EPtrs { const float* p[8]; };

__device__ __forceinline__ u16 f2bf(float x){
  unsigned u = __float_as_uint(x);
  unsigned r = (u + 0x7fffu + ((u >> 16) & 1u)) >> 16;   // RNE
  return (u16)r;
}
__device__ __forceinline__ float bf2f(u16 v){
  return __uint_as_float(((unsigned)v) << 16);
}
__device__ __forceinline__ u16 f2h(float x){
  _Float16 h = (_Float16)x;
  u16 r; __builtin_memcpy(&r, &h, 2);
  return r;
}
// monotone float<->uint map for deterministic atomic min/max
__device__ __forceinline__ unsigned fenc(float x){
  unsigned u = __float_as_uint(x);
  return (u & 0x80000000u) ? ~u : (u | 0x80000000u);
}
__device__ __forceinline__ float fdec(unsigned u){
  unsigned v = (u & 0x80000000u) ? (u & 0x7fffffffu) : ~u;
  return __uint_as_float(v);
}

// ---------------- init atomics ----------------
__global__ void k_init(unsigned* mmxe, unsigned* mmxa){
  int t = threadIdx.x;
  if (t < 8){ mmxe[2*t] = 0xFFFFFFFFu; mmxe[2*t+1] = 0u; }
  if (t == 8){ mmxa[0] = 0xFFFFFFFFu; mmxa[1] = 0u; }
}

// ---------------- weight re-layout: w1[oc][ic][k9] -> w1m[icc][k9][oc][ic32] f16 ----------------
__global__ void k_prep(const float* __restrict__ w1, u16* __restrict__ w1m){
  int i = blockIdx.x*256 + threadIdx.x;
  if (i < 73728){
    int ic32 = i & 31;
    int oc   = (i >> 5) & 63;
    int k9   = (i >> 11) % 9;
    int icc  = i / 18432;
    float v = w1[(oc*128 + icc*32 + ic32)*9 + k9];
    w1m[i] = f2h(v);
  }
}

// ---------------- per-tensor stats + Gram partials (MFMA bf16) ----------------
// grid 256 = 8 tensors * 4 batch * 8 slices(2048 n each). block 256.
__global__ __launch_bounds__(256) void k_stats_gram(EPtrs eps,
    float* __restrict__ gram, float* __restrict__ sump, unsigned* __restrict__ mmxe){
  int bid = blockIdx.x;
  int t = bid >> 5; int rb = bid & 31; int b = rb >> 3; int s = rb & 7;
  const float* E = eps.p[t];
  __shared__ u16 lds[64*136];           // [c][n(128)+pad8] bf16
  __shared__ float red[768];
  int tid = threadIdx.x;
  int lane = tid & 63, wave = tid >> 6;
  f32x4 acc[4];
  #pragma unroll
  for (int i=0;i<4;++i) acc[i] = (f32x4){0.f,0.f,0.f,0.f};
  float vmin = 3.4e38f, vmax = -3.4e38f, vsum = 0.f;
  int rowS = tid >> 5;            // 0..7
  int colS = (tid & 31) * 4;      // 0..124
  int rA = wave*16 + (lane & 15);
  int kb = (lane >> 4) * 8;
  long nbase = (long)s * 2048;
  for (int ch = 0; ch < 16; ++ch){
    long n0 = nbase + ch*128;
    __syncthreads();
    #pragma unroll
    for (int p = 0; p < 8; ++p){
      int row = p*8 + rowS;
      f4 v = *(const f4*)&E[(long)(b*64 + row)*NPIX + n0 + colS];
      vsum += v[0]+v[1]+v[2]+v[3];
      vmin = fminf(vmin, fminf(fminf(v[0],v[1]), fminf(v[2],v[3])));
      vmax = fmaxf(vmax, fmaxf(fmaxf(v[0],v[1]), fmaxf(v[2],v[3])));
      u16x4 w; w[0]=f2bf(v[0]); w[1]=f2bf(v[1]); w[2]=f2bf(v[2]); w[3]=f2bf(v[3]);
      *(u16x4*)&lds[row*136 + colS] = w;
    }
    __syncthreads();
    #pragma unroll
    for (int ks = 0; ks < 4; ++ks){
      bf16x8 a = *(bf16x8*)&lds[rA*136 + ks*32 + kb];
      #pragma unroll
      for (int cb = 0; cb < 4; ++cb){
        bf16x8 bb = *(bf16x8*)&lds[(cb*16 + (lane&15))*136 + ks*32 + kb];
        acc[cb] = __builtin_amdgcn_mfma_f32_16x16x32_bf16(a, bb, acc[cb], 0, 0, 0);
      }
    }
  }
  // gram partial write: S[c][d], c = 16*wave + 4*(lane>>4)+rr, d = 16*cb + (lane&15)
  long gbase = ((long)((t*4 + b)*8 + s)) * 4096;
  #pragma unroll
  for (int cb = 0; cb < 4; ++cb){
    int d = cb*16 + (lane & 15);
    #pragma unroll
    for (int rr = 0; rr < 4; ++rr){
      int c = 16*wave + 4*(lane>>4) + rr;
      gram[gbase + c*64 + d] = acc[cb][rr];
    }
  }
  // stats reduce
  red[tid] = vsum; red[256+tid] = vmin; red[512+tid] = vmax;
  __syncthreads();
  for (int off = 128; off > 0; off >>= 1){
    if (tid < off){
      red[tid] += red[tid+off];
      red[256+tid] = fminf(red[256+tid], red[256+tid+off]);
      red[512+tid] = fmaxf(red[512+tid], red[512+tid+off]);
    }
    __syncthreads();
  }
  if (tid == 0){
    sump[t*32 + b*8 + s] = red[0];
    atomicMin(&mmxe[2*t], fenc(red[256]));
    atomicMax(&mmxe[2*t+1], fenc(red[512]));
  }
}

// ---------------- finalize per-tensor scalars ----------------
__global__ void k_finalize(const float* __restrict__ sump, const unsigned* __restrict__ mmxe,
                           float* __restrict__ meanA, float* __restrict__ mntA, float* __restrict__ invA){
  int t = threadIdx.x;
  if (t < 8){
    float s = 0.f;
    for (int j = 0; j < 32; ++j) s += sump[t*32 + j];
    float mean = s / 4194304.0f;
    float mn = fdec(mmxe[2*t]), mx = fdec(mmxe[2*t+1]);
    float mnt = fmaxf(mn - mean, 1e-10f);
    float mxt = fmaxf(mx - mean, 1e-10f);
    meanA[t] = mean; mntA[t] = mnt;
    invA[t] = 1.0f / (mxt - mnt + 1e-10f);
  }
}

// ---------------- softmax over axis=1 (rows c, per column d) ----------------
// grid 32 = (t,b). W[c][d] bf16 written to Wb.
__global__ void k_softmax(const float* __restrict__ gram, u16* __restrict__ Wb){
  int bid = blockIdx.x; int t = bid >> 2; int b = bid & 3;
  __shared__ float S[64*65];
  int tid = threadIdx.x;
  long gb = (long)(t*4 + b)*8*4096;
  for (int i = tid; i < 4096; i += 256){
    float v = 0.f;
    for (int s = 0; s < 8; ++s) v += gram[gb + s*4096 + i];
    S[(i>>6)*65 + (i&63)] = v;
  }
  __syncthreads();
  if (tid < 64){
    int d = tid;
    float mx = -3.4e38f;
    for (int c = 0; c < 64; ++c) mx = fmaxf(mx, S[c*65+d]);
    float sum = 0.f;
    for (int c = 0; c < 64; ++c){ float e = expf(S[c*65+d]-mx); S[c*65+d] = e; sum += e; }
    float inv = 1.0f/sum;
    long wb = (long)(t*4 + b)*4096;
    for (int c = 0; c < 64; ++c) Wb[wb + c*64 + d] = f2bf(S[c*65+d]*inv);
  }
}

// ---------------- conv1 3x3 implicit-GEMM MFMA f16 + bias + leaky ----------------
// grid 512 = (b,h) XCD-swizzled. block 512 = 8 waves: wave = (mg 2) x (ng 4).
// per block: 64 oc x 128 w (one image row). K = 4 icc-chunks * 9 khkw * 32 ic.
__global__ __launch_bounds__(512) void k_conv1(const float* __restrict__ fc,
    const u16* __restrict__ w1m, const float* __restrict__ b1, float* __restrict__ cat){
  int bid = blockIdx.x;
  int vb = (bid & 7)*64 + (bid >> 3);      // XCD-chunked: contiguous h-bands per XCD
  int b = vb >> 7, h = vb & 127;
  __shared__ u16 xin[32*3*140];            // [ic32][r3][s140] f16 bits; s = w_in + 4
  int tid = threadIdx.x;
  int lane = tid & 63, wv = tid >> 6;
  int mg = wv >> 2, ng = wv & 3;
  int l15 = lane & 15, lq = lane >> 4;
  // zero halo cols s=3 (w=-1) and s=132 (w=128); staging never touches them
  if (tid < 192){
    int ic = tid / 6, rem = tid % 6;
    int r = rem >> 1, sx = (rem & 1) ? 132 : 3;
    xin[(ic*3 + r)*140 + sx] = 0;
  }
  f32x4 acc[2][2];
  #pragma unroll
  for (int i=0;i<2;++i)
    #pragma unroll
    for (int j=0;j<2;++j) acc[i][j] = (f32x4){0.f,0.f,0.f,0.f};
  for (int icc = 0; icc < 4; ++icc){
    __syncthreads();
    // stage 32 ic x 3 rows x 128 w (f32 -> f16), coalesced f4 reads
    #pragma unroll
    for (int it = 0; it < 6; ++it){
      int idx = tid + it*512;              // < 3072
      int ic = idx / 96, rem = idx % 96;
      int r = rem >> 5, q = rem & 31;
      int hr = h + r - 1;
      f4 v = (f4){0.f,0.f,0.f,0.f};
      if ((unsigned)hr < 128u)
        v = *(const f4*)&fc[(long)((b*128 + icc*32 + ic)*128 + hr)*128 + 4*q];
      u16x4 w; w[0]=f2h(v[0]); w[1]=f2h(v[1]); w[2]=f2h(v[2]); w[3]=f2h(v[3]);
      *(u16x4*)&xin[(ic*3 + r)*140 + 4 + 4*q] = w;
    }
    __syncthreads();
    #pragma unroll
    for (int kh = 0; kh < 3; ++kh){
      #pragma unroll
      for (int kw = 0; kw < 3; ++kw){
        int k9 = kh*3 + kw;
        f16x8 A[2];
        #pragma unroll
        for (int mi = 0; mi < 2; ++mi){
          int m = mg*2 + mi;
          A[mi] = *(const f16x8*)&w1m[(((icc*9 + k9)*64) + m*16 + l15)*32 + lq*8];
        }
        #pragma unroll
        for (int ji = 0; ji < 2; ++ji){
          int s = ng*32 + ji*16 + l15 + kw + 3;   // input col window
          int kb = lq*8;
          f16x8 bv;
          #pragma unroll
          for (int e = 0; e < 8; ++e){
            u16 raw = xin[((kb + e)*3 + kh)*140 + s];
            _Float16 hh; __builtin_memcpy(&hh, &raw, 2);
            bv[e] = hh;
          }
          acc[0][ji] = __builtin_amdgcn_mfma_f32_16x16x32_f16(A[0], bv, acc[0][ji], 0, 0, 0);
          acc[1][ji] = __builtin_amdgcn_mfma_f32_16x16x32_f16(A[1], bv, acc[1][ji], 0, 0, 0);
        }
      }
    }
  }
  // epilogue: bias + leaky, coalesced per 16-lane group
  #pragma unroll
  for (int mi = 0; mi < 2; ++mi){
    #pragma unroll
    for (int rr = 0; rr < 4; ++rr){
      int oc = (mg*2 + mi)*16 + lq*4 + rr;
      float bb = b1[oc];
      #pragma unroll
      for (int ji = 0; ji < 2; ++ji){
        int w = ng*32 + ji*16 + l15;
        float v = acc[mi][ji][rr] + bb;
        v = v > 0.f ? v : 0.01f*v;
        cat[(long)((b*64 + oc)*128 + h)*128 + w] = v;
      }
    }
  }
}

// ---------------- conv2 3x3 (64ch -> 1) + bias, plus global min/max of result ----------------
// grid 512 = (b,h). block 256.
__global__ __launch_bounds__(256) void k_conv2(const float* __restrict__ cat,
    const float* __restrict__ w2, const float* __restrict__ b2p,
    float* __restrict__ am, unsigned* __restrict__ mmxa){
  int bid = blockIdx.x; int b = bid >> 7; int h = bid & 127;
  __shared__ u16 l2[64*3*132];
  __shared__ float w2l[576];
  __shared__ float red2[256];
  int tid = threadIdx.x;
  for (int i = tid; i < 576; i += 256) w2l[i] = w2[i];
  for (int i = tid; i < 25344; i += 256){
    int ic = i / 396; int rem = i - ic*396; int r = rem / 132; int cl = rem - r*132;
    int w = cl - 1; int hr = h + r - 1;
    float v = 0.f;
    if ((unsigned)w < 128u && (unsigned)hr < 128u && cl < 130)
      v = cat[(long)((b*64 + ic)*128 + hr)*128 + w];
    l2[i] = f2bf(v);
  }
  __syncthreads();
  int w = tid & 127, icg = tid >> 7;
  float a = 0.f;
  for (int ic = icg*32; ic < icg*32+32; ++ic){
    #pragma unroll
    for (int r = 0; r < 3; ++r)
      #pragma unroll
      for (int kw = 0; kw < 3; ++kw)
        a = fmaf(bf2f(l2[ic*396 + r*132 + (w + kw)]), w2l[ic*9 + r*3 + kw], a);
  }
  red2[tid] = a;
  __syncthreads();
  float av = 0.f;
  if (icg == 0){
    av = red2[w] + red2[128 + w] + b2p[0];
    am[(long)(b*128 + h)*128 + w] = av;
  }
  __syncthreads();
  red2[tid] = (icg == 0) ? av : -3.4e38f;
  __syncthreads();
  for (int off = 128; off > 0; off >>= 1){
    if (tid < off) red2[tid] = fmaxf(red2[tid], red2[tid+off]);
    __syncthreads();
  }
  if (tid == 0) atomicMax(&mmxa[1], fenc(red2[0]));
  __syncthreads();
  red2[tid] = (icg == 0) ? av : 3.4e38f;
  __syncthreads();
  for (int off = 128; off > 0; off >>= 1){
    if (tid < off) red2[tid] = fminf(red2[tid], red2[tid+off]);
    __syncthreads();
  }
  if (tid == 0) atomicMin(&mmxa[0], fenc(red2[0]));
}

// ---------------- Ir/Vi maps ----------------
__global__ void k_maps(const float* __restrict__ cat, const float* __restrict__ am,
                       const unsigned* __restrict__ mmxa, float* __restrict__ out){
  long e = ((long)blockIdx.x*256 + threadIdx.x) * 4;   // over 4,194,304 cat elems
  float mn = fdec(mmxa[0]);
  float inv = 1.0f / (fdec(mmxa[1]) - mn + 1e-10f);
  f4 c = *(const f4*)&cat[e];
  f4 a = *(const f4*)&am[(e >> 20)*16384 + (e & 16383)];
  f4 nam = (a - mn) * inv;
  f4 ir = nam * c;
  f4 vi = (1.0f - nam) * c;
  *(f4*)&out[O_IR + e] = ir;
  *(f4*)&out[O_VI + e] = vi;
}

// ---------------- fuse: fw = W*fr (MFMA) + norm-term + f, write M & flat copy ----------------
// grid 2048 = 8t * 4b * 64 ntile(256). block 256.
__global__ __launch_bounds__(256) void k_fuse(EPtrs eps, const u16* __restrict__ Wb,
    const float* __restrict__ meanA, const float* __restrict__ mntA, const float* __restrict__ invA,
    float* __restrict__ out){
  int bid = blockIdx.x;
  int t = bid >> 8; int rem = bid & 255; int b = rem >> 6; int nt = rem & 63;
  long n0 = (long)nt * 256;
  const float* E = eps.p[t];
  __shared__ u16 fr[64*260];     // [d][n(256)+pad4] bf16
  __shared__ u16 Wl[64*72];      // [c][d(64)+pad8] bf16
  int tid = threadIdx.x; int lane = tid & 63; int wave = tid >> 6;
  { long wb = (long)(t*4 + b)*4096;
    for (int i = tid; i < 4096; i += 256) Wl[(i>>6)*72 + (i&63)] = Wb[wb + i]; }
  #pragma unroll 4
  for (int i = 0; i < 16; ++i){
    int r = wave + 4*i;
    f4 v = *(const f4*)&E[(long)(b*64 + r)*NPIX + n0 + 4*lane];
    u16x4 u; u[0]=f2bf(v[0]); u[1]=f2bf(v[1]); u[2]=f2bf(v[2]); u[3]=f2bf(v[3]);
    *(u16x4*)&fr[r*260 + 4*lane] = u;
  }
  __syncthreads();
  f32x4 acc[16];
  #pragma unroll
  for (int i = 0; i < 16; ++i) acc[i] = (f32x4){0.f,0.f,0.f,0.f};
  int kb = (lane >> 4) * 8; int jc = lane & 15;
  #pragma unroll
  for (int ks = 0; ks < 2; ++ks){
    bf16x8 a = *(bf16x8*)&Wl[(wave*16 + jc)*72 + ks*32 + kb];
    #pragma unroll
    for (int j0 = 0; j0 < 16; ++j0){
      bf16x8 bv;
      #pragma unroll
      for (int e8 = 0; e8 < 8; ++e8)
        bv[e8] = (short)fr[(ks*32 + kb + e8)*260 + j0*16 + jc];
      acc[j0] = __builtin_amdgcn_mfma_f32_16x16x32_bf16(a, bv, acc[j0], 0, 0, 0);
    }
  }
  float mean = meanA[t], mnt = mntA[t], inv = invA[t];
  long Mbase = (t & 1) ? O_M2 : O_M1;
  long g = t >> 1;
  int rbase = wave*16 + (lane>>4)*4;
  #pragma unroll
  for (int j0 = 0; j0 < 16; ++j0){
    long n = n0 + j0*16 + jc;
    #pragma unroll
    for (int rr = 0; rr < 4; ++rr){
      int c = rbase + rr;
      float f = E[(long)(b*64 + c)*NPIX + n];
      float tv = fmaxf(f - mean, 1e-10f);
      float val = (tv - mnt)*inv + acc[j0][rr] + f;
      long dst = Mbase + ((long)(b*256 + g*64 + c))*NPIX + n;
      out[dst] = val;
      out[dst + FLATD] = val;
    }
  }
}

// ---------------- activation outputs (reads am in-place from ViA region) ----------------
__global__ void k_acts(const unsigned* __restrict__ mmxa, float* __restrict__ out){
  long e = ((long)blockIdx.x*256 + threadIdx.x) * 4;   // 65536 elems
  float mn = fdec(mmxa[0]);
  float inv = 1.0f / (fdec(mmxa[1]) - mn + 1e-10f);
  f4 a = *(const f4*)&out[O_VIA + e];
  f4 nam = (a - mn) * inv;
  *(f4*)&out[O_IRA + e] = nam;
  *(f4*)&out[O_VIA + e] = 1.0f - nam;
}

extern "C" void kernel_launch(void* const* d_in, const int* in_sizes, int n_in,
                              void* d_out, int out_size, void* d_ws, size_t ws_size,
                              hipStream_t stream){
  (void)in_sizes; (void)n_in; (void)out_size; (void)ws_size;
  EPtrs ep;
  for (int i = 0; i < 8; ++i) ep.p[i] = (const float*)d_in[i];
  const float* fc = (const float*)d_in[8];
  const float* w1 = (const float*)d_in[9];
  const float* b1 = (const float*)d_in[10];
  const float* w2 = (const float*)d_in[11];
  const float* b2 = (const float*)d_in[12];
  float* out = (float*)d_out;
  char* ws = (char*)d_ws;
  float* sump   = (float*)(ws + WS_SUMP);
  unsigned* mmxe = (unsigned*)(ws + WS_MMXE);
  unsigned* mmxa = (unsigned*)(ws + WS_MMXA);
  float* meanA  = (float*)(ws + WS_MEAN);
  float* mntA   = (float*)(ws + WS_MNT);
  float* invA   = (float*)(ws + WS_INV);
  u16*   w1m    = (u16*)(ws + WS_W1M);
  // d_out-aliased scratch (each consumed before its real output is written):
  float* gram = out + O_M1F;            // consumed by k_softmax, overwritten by k_fuse
  float* cat  = out + O_M2F;            // consumed by k_conv2/k_maps, overwritten by k_fuse
  u16*   Wb   = (u16*)(out + O_IRA);    // consumed by k_fuse, overwritten by k_acts
  float* am   = out + O_VIA;            // consumed by k_maps/k_acts (in-place)

  k_init      <<<1,    64, 0, stream>>>(mmxe, mmxa);
  k_prep      <<<288, 256, 0, stream>>>(w1, w1m);
  k_stats_gram<<<256, 256, 0, stream>>>(ep, gram, sump, mmxe);
  k_finalize  <<<1,    64, 0, stream>>>(sump, mmxe, meanA, mntA, invA);
  k_softmax   <<<32,  256, 0, stream>>>(gram, Wb);
  k_conv1     <<<512, 512, 0, stream>>>(fc, w1m, b1, cat);
  k_conv2     <<<512, 256, 0, stream>>>(cat, w2, b2, am, mmxa);
  k_maps      <<<4096,256, 0, stream>>>(cat, am, mmxa, out);
  k_fuse      <<<2048,256, 0, stream>>>(ep, Wb, meanA, mntA, invA, out);
  k_acts      <<<64,  256, 0, stream>>>(mmxa, out);
}

// Round 3
// 246.575 us; speedup vs baseline: 1.7625x; 1.1738x over previous
//
#include <hip/hip_runtime.h>
#include <stdint.h>
#include <math.h>

typedef float f4 __attribute__((ext_vector_type(4)));
typedef float f32x4 __attribute__((ext_vector_type(4)));
typedef short bf16x8 __attribute__((ext_vector_type(8)));
typedef _Float16 f16x8 __attribute__((ext_vector_type(8)));
typedef unsigned short u16;
typedef unsigned short u16x4 __attribute__((ext_vector_type(4)));

#define NPIX 16384

// d_out offsets (floats). Return order: M1, M2, M1flat, M2flat, Ir_map, Vi_map, IrA, ViA
#define O_M1   0l
#define O_M2   16777216l
#define O_M1F  33554432l
#define O_M2F  50331648l
#define O_IR   67108864l
#define O_VI   71303168l
#define O_IRA  75497472l
#define O_VIA  75563008l
#define FLATD  33554432l   // offset from M to its flat duplicate (same for M1,M2)

// ws offsets (bytes)
#define WS_SUMP 0        // 1024 floats (8t * 4b * 32s)
#define WS_MMXE 4096     // 16 uints (per tensor min/max encoded)
#define WS_MMXA 4160     // 2 uints (activation map min/max)
#define WS_MEAN 4224     // 8 floats
#define WS_MNT  4256     // 8 floats
#define WS_INV  4288     // 8 floats
#define WS_W1M  8192     // 73728 u16, w1 as f16 relaid [icc][k9][oc][ic]

struct EPtrs { const float* p[8]; };

__device__ __forceinline__ u16 f2bf(float x){
  unsigned u = __float_as_uint(x);
  unsigned r = (u + 0x7fffu + ((u >> 16) & 1u)) >> 16;   // RNE
  return (u16)r;
}
__device__ __forceinline__ float bf2f(u16 v){
  return __uint_as_float(((unsigned)v) << 16);
}
__device__ __forceinline__ u16 f2h(float x){
  _Float16 h = (_Float16)x;
  u16 r; __builtin_memcpy(&r, &h, 2);
  return r;
}
// monotone float<->uint map for deterministic atomic min/max
__device__ __forceinline__ unsigned fenc(float x){
  unsigned u = __float_as_uint(x);
  return (u & 0x80000000u) ? ~u : (u | 0x80000000u);
}
__device__ __forceinline__ float fdec(unsigned u){
  unsigned v = (u & 0x80000000u) ? (u & 0x7fffffffu) : ~u;
  return __uint_as_float(v);
}

// ---------------- weight re-layout (+ atomic init in block 0) ----------------
__global__ void k_prep(const float* __restrict__ w1, u16* __restrict__ w1m,
                       unsigned* mmxe, unsigned* mmxa){
  if (blockIdx.x == 0 && threadIdx.x < 9){
    int t = threadIdx.x;
    if (t < 8){ mmxe[2*t] = 0xFFFFFFFFu; mmxe[2*t+1] = 0u; }
    else      { mmxa[0] = 0xFFFFFFFFu; mmxa[1] = 0u; }
  }
  int i = blockIdx.x*256 + threadIdx.x;
  if (i < 73728){
    int ic32 = i & 31;
    int oc   = (i >> 5) & 63;
    int k9   = (i >> 11) % 9;
    int icc  = i / 18432;
    float v = w1[(oc*128 + icc*32 + ic32)*9 + k9];
    w1m[i] = f2h(v);
  }
}

// ---------------- per-tensor stats + Gram partials (MFMA bf16) ----------------
// grid 1024 = 8 tensors * 4 batch * 32 slices(512 n each). block 256.
__global__ __launch_bounds__(256) void k_stats_gram(EPtrs eps,
    float* __restrict__ gram, float* __restrict__ sump, unsigned* __restrict__ mmxe){
  int bid = blockIdx.x;
  int t = bid >> 7; int rb = bid & 127; int b = rb >> 5; int s = rb & 31;
  const float* E = eps.p[t];
  __shared__ u16 lds[64*136];           // [c][n(128)+pad8] bf16
  __shared__ float red[768];
  int tid = threadIdx.x;
  int lane = tid & 63, wave = tid >> 6;
  f32x4 acc[4];
  #pragma unroll
  for (int i=0;i<4;++i) acc[i] = (f32x4){0.f,0.f,0.f,0.f};
  float vmin = 3.4e38f, vmax = -3.4e38f, vsum = 0.f;
  int rowS = tid >> 5;            // 0..7
  int colS = (tid & 31) * 4;      // 0..124
  int rA = wave*16 + (lane & 15);
  int kb = (lane >> 4) * 8;
  long nbase = (long)s * 512;
  for (int ch = 0; ch < 4; ++ch){
    long n0 = nbase + ch*128;
    __syncthreads();
    #pragma unroll
    for (int p = 0; p < 8; ++p){
      int row = p*8 + rowS;
      f4 v = *(const f4*)&E[(long)(b*64 + row)*NPIX + n0 + colS];
      vsum += v[0]+v[1]+v[2]+v[3];
      vmin = fminf(vmin, fminf(fminf(v[0],v[1]), fminf(v[2],v[3])));
      vmax = fmaxf(vmax, fmaxf(fmaxf(v[0],v[1]), fmaxf(v[2],v[3])));
      u16x4 w; w[0]=f2bf(v[0]); w[1]=f2bf(v[1]); w[2]=f2bf(v[2]); w[3]=f2bf(v[3]);
      *(u16x4*)&lds[row*136 + colS] = w;
    }
    __syncthreads();
    #pragma unroll
    for (int ks = 0; ks < 4; ++ks){
      bf16x8 a = *(bf16x8*)&lds[rA*136 + ks*32 + kb];
      #pragma unroll
      for (int cb = 0; cb < 4; ++cb){
        bf16x8 bb = *(bf16x8*)&lds[(cb*16 + (lane&15))*136 + ks*32 + kb];
        acc[cb] = __builtin_amdgcn_mfma_f32_16x16x32_bf16(a, bb, acc[cb], 0, 0, 0);
      }
    }
  }
  // gram partial write: S[c][d], c = 16*wave + 4*(lane>>4)+rr, d = 16*cb + (lane&15)
  long gbase = ((long)((t*4 + b)*32 + s)) * 4096;
  #pragma unroll
  for (int cb = 0; cb < 4; ++cb){
    int d = cb*16 + (lane & 15);
    #pragma unroll
    for (int rr = 0; rr < 4; ++rr){
      int c = 16*wave + 4*(lane>>4) + rr;
      gram[gbase + c*64 + d] = acc[cb][rr];
    }
  }
  // stats reduce
  red[tid] = vsum; red[256+tid] = vmin; red[512+tid] = vmax;
  __syncthreads();
  for (int off = 128; off > 0; off >>= 1){
    if (tid < off){
      red[tid] += red[tid+off];
      red[256+tid] = fminf(red[256+tid], red[256+tid+off]);
      red[512+tid] = fmaxf(red[512+tid], red[512+tid+off]);
    }
    __syncthreads();
  }
  if (tid == 0){
    sump[t*128 + b*32 + s] = red[0];
    atomicMin(&mmxe[2*t], fenc(red[256]));
    atomicMax(&mmxe[2*t+1], fenc(red[512]));
  }
}

// ---------------- softmax over axis=1 + per-tensor scalar finalize ----------------
// grid 32 = (t,b). W[c][d] bf16 written to Wb.
__global__ void k_softmax(const float* __restrict__ gram, u16* __restrict__ Wb,
                          const float* __restrict__ sump, const unsigned* __restrict__ mmxe,
                          float* __restrict__ meanA, float* __restrict__ mntA, float* __restrict__ invA){
  int bid = blockIdx.x; int t = bid >> 2; int b = bid & 3;
  __shared__ float S[64*65];
  int tid = threadIdx.x;
  // fold finalize into b==0 block (used only by later k_fuse)
  if (b == 0 && tid == 0){
    float s = 0.f;
    for (int j = 0; j < 128; ++j) s += sump[t*128 + j];
    float mean = s / 4194304.0f;
    float mn = fdec(mmxe[2*t]), mx = fdec(mmxe[2*t+1]);
    float mnt = fmaxf(mn - mean, 1e-10f);
    float mxt = fmaxf(mx - mean, 1e-10f);
    meanA[t] = mean; mntA[t] = mnt;
    invA[t] = 1.0f / (mxt - mnt + 1e-10f);
  }
  long gb = (long)(t*4 + b)*32*4096;
  for (int i = tid; i < 4096; i += 256){
    float v = 0.f;
    for (int s = 0; s < 32; ++s) v += gram[gb + s*4096 + i];
    S[(i>>6)*65 + (i&63)] = v;
  }
  __syncthreads();
  if (tid < 64){
    int d = tid;
    float mx = -3.4e38f;
    for (int c = 0; c < 64; ++c) mx = fmaxf(mx, S[c*65+d]);
    float sum = 0.f;
    for (int c = 0; c < 64; ++c){ float e = expf(S[c*65+d]-mx); S[c*65+d] = e; sum += e; }
    float inv = 1.0f/sum;
    long wb = (long)(t*4 + b)*4096;
    for (int c = 0; c < 64; ++c) Wb[wb + c*64 + d] = f2bf(S[c*65+d]*inv);
  }
}

// ---------------- conv1 3x3 implicit-GEMM MFMA f16 + bias + leaky ----------------
// grid 512 = (b,h) XCD-swizzled. block 512 = 8 waves: wave = (mg 2) x (ng 4).
__global__ __launch_bounds__(512) void k_conv1(const float* __restrict__ fc,
    const u16* __restrict__ w1m, const float* __restrict__ b1, float* __restrict__ cat){
  int bid = blockIdx.x;
  int vb = (bid & 7)*64 + (bid >> 3);      // XCD-chunked: contiguous h-bands per XCD
  int b = vb >> 7, h = vb & 127;
  __shared__ u16 xin[32*3*140];            // [ic32][r3][s140] f16 bits; s = w_in + 4
  int tid = threadIdx.x;
  int lane = tid & 63, wv = tid >> 6;
  int mg = wv >> 2, ng = wv & 3;
  int l15 = lane & 15, lq = lane >> 4;
  if (tid < 192){
    int ic = tid / 6, rem = tid % 6;
    int r = rem >> 1, sx = (rem & 1) ? 132 : 3;
    xin[(ic*3 + r)*140 + sx] = 0;
  }
  f32x4 acc[2][2];
  #pragma unroll
  for (int i=0;i<2;++i)
    #pragma unroll
    for (int j=0;j<2;++j) acc[i][j] = (f32x4){0.f,0.f,0.f,0.f};
  for (int icc = 0; icc < 4; ++icc){
    __syncthreads();
    #pragma unroll
    for (int it = 0; it < 6; ++it){
      int idx = tid + it*512;              // < 3072
      int ic = idx / 96, rem = idx % 96;
      int r = rem >> 5, q = rem & 31;
      int hr = h + r - 1;
      f4 v = (f4){0.f,0.f,0.f,0.f};
      if ((unsigned)hr < 128u)
        v = *(const f4*)&fc[(long)((b*128 + icc*32 + ic)*128 + hr)*128 + 4*q];
      u16x4 w; w[0]=f2h(v[0]); w[1]=f2h(v[1]); w[2]=f2h(v[2]); w[3]=f2h(v[3]);
      *(u16x4*)&xin[(ic*3 + r)*140 + 4 + 4*q] = w;
    }
    __syncthreads();
    #pragma unroll
    for (int kh = 0; kh < 3; ++kh){
      #pragma unroll
      for (int kw = 0; kw < 3; ++kw){
        int k9 = kh*3 + kw;
        f16x8 A[2];
        #pragma unroll
        for (int mi = 0; mi < 2; ++mi){
          int m = mg*2 + mi;
          A[mi] = *(const f16x8*)&w1m[(((icc*9 + k9)*64) + m*16 + l15)*32 + lq*8];
        }
        #pragma unroll
        for (int ji = 0; ji < 2; ++ji){
          int s = ng*32 + ji*16 + l15 + kw + 3;
          int kb = lq*8;
          f16x8 bv;
          #pragma unroll
          for (int e = 0; e < 8; ++e){
            u16 raw = xin[((kb + e)*3 + kh)*140 + s];
            _Float16 hh; __builtin_memcpy(&hh, &raw, 2);
            bv[e] = hh;
          }
          acc[0][ji] = __builtin_amdgcn_mfma_f32_16x16x32_f16(A[0], bv, acc[0][ji], 0, 0, 0);
          acc[1][ji] = __builtin_amdgcn_mfma_f32_16x16x32_f16(A[1], bv, acc[1][ji], 0, 0, 0);
        }
      }
    }
  }
  #pragma unroll
  for (int mi = 0; mi < 2; ++mi){
    #pragma unroll
    for (int rr = 0; rr < 4; ++rr){
      int oc = (mg*2 + mi)*16 + lq*4 + rr;
      float bb = b1[oc];
      #pragma unroll
      for (int ji = 0; ji < 2; ++ji){
        int w = ng*32 + ji*16 + l15;
        float v = acc[mi][ji][rr] + bb;
        v = v > 0.f ? v : 0.01f*v;
        cat[(long)((b*64 + oc)*128 + h)*128 + w] = v;
      }
    }
  }
}

// ---------------- conv2 3x3 (64ch -> 1) + bias, plus global min/max of result ----------------
// grid 512 = (b,h). block 256. LDS core at cl = w_in + 4 (8B-aligned staging).
__global__ __launch_bounds__(256) void k_conv2(const float* __restrict__ cat,
    const float* __restrict__ w2, const float* __restrict__ b2p,
    float* __restrict__ am, unsigned* __restrict__ mmxa){
  int bid = blockIdx.x; int b = bid >> 7; int h = bid & 127;
  __shared__ u16 l2[64*3*136];
  __shared__ float w2l[576];
  __shared__ float red2[256];
  int tid = threadIdx.x;
  for (int i = tid; i < 576; i += 256) w2l[i] = w2[i];
  if (tid < 192){
    int ic = tid / 3, r = tid % 3;
    l2[ic*408 + r*136 + 3]   = 0;   // w_in = -1
    l2[ic*408 + r*136 + 132] = 0;   // w_in = 128
  }
  #pragma unroll
  for (int rep = 0; rep < 3; ++rep){
    int idx = rep*256 + tid;             // < 768 = 64ic * 3r * 4q
    int ic = idx / 12; int rem = idx - ic*12; int r = rem >> 2; int q = rem & 3;
    int hr = h + r - 1;
    #pragma unroll
    for (int k = 0; k < 8; ++k){
      int w = q*32 + 4*k;
      f4 v = (f4){0.f,0.f,0.f,0.f};
      if ((unsigned)hr < 128u)
        v = *(const f4*)&cat[(long)((b*64 + ic)*128 + hr)*128 + w];
      u16x4 u; u[0]=f2bf(v[0]); u[1]=f2bf(v[1]); u[2]=f2bf(v[2]); u[3]=f2bf(v[3]);
      *(u16x4*)&l2[ic*408 + r*136 + 4 + w] = u;
    }
  }
  __syncthreads();
  int w = tid & 127, icg = tid >> 7;
  float a = 0.f;
  for (int ic = icg*32; ic < icg*32+32; ++ic){
    #pragma unroll
    for (int r = 0; r < 3; ++r)
      #pragma unroll
      for (int kw = 0; kw < 3; ++kw)
        a = fmaf(bf2f(l2[ic*408 + r*136 + (w + kw + 3)]), w2l[ic*9 + r*3 + kw], a);
  }
  red2[tid] = a;
  __syncthreads();
  float av = 0.f;
  if (icg == 0){
    av = red2[w] + red2[128 + w] + b2p[0];
    am[(long)(b*128 + h)*128 + w] = av;
  }
  __syncthreads();
  red2[tid] = (icg == 0) ? av : -3.4e38f;
  __syncthreads();
  for (int off = 128; off > 0; off >>= 1){
    if (tid < off) red2[tid] = fmaxf(red2[tid], red2[tid+off]);
    __syncthreads();
  }
  if (tid == 0) atomicMax(&mmxa[1], fenc(red2[0]));
  __syncthreads();
  red2[tid] = (icg == 0) ? av : 3.4e38f;
  __syncthreads();
  for (int off = 128; off > 0; off >>= 1){
    if (tid < off) red2[tid] = fminf(red2[tid], red2[tid+off]);
    __syncthreads();
  }
  if (tid == 0) atomicMin(&mmxa[0], fenc(red2[0]));
}

// ---------------- Ir/Vi maps ----------------
__global__ void k_maps(const float* __restrict__ cat, const float* __restrict__ am,
                       const unsigned* __restrict__ mmxa, float* __restrict__ out){
  long e = ((long)blockIdx.x*256 + threadIdx.x) * 4;
  float mn = fdec(mmxa[0]);
  float inv = 1.0f / (fdec(mmxa[1]) - mn + 1e-10f);
  f4 c = *(const f4*)&cat[e];
  f4 a = *(const f4*)&am[(e >> 20)*16384 + (e & 16383)];
  f4 nam = (a - mn) * inv;
  f4 ir = nam * c;
  f4 vi = (1.0f - nam) * c;
  *(f4*)&out[O_IR + e] = ir;
  *(f4*)&out[O_VI + e] = vi;
}

// ---------------- fuse: fw = W*fr (MFMA, no LDS) + norm-term + f, write M & flat ----------------
// grid 2048 = 8t*4b*64nt(256 n). block 256 = 4 waves; wave w -> n-range n0+w*64 (all 64 c).
__global__ __launch_bounds__(256) void k_fuse(EPtrs eps, const u16* __restrict__ Wb,
    const float* __restrict__ meanA, const float* __restrict__ mntA, const float* __restrict__ invA,
    float* __restrict__ out){
  int bid = blockIdx.x;
  int t = bid >> 8; int rem = bid & 255; int b = rem >> 6; int nt = rem & 63;
  const float* E = eps.p[t];
  const u16* Wp = Wb + (long)(t*4 + b)*4096;
  int tid = threadIdx.x; int lane = tid & 63; int w = tid >> 6;
  int jc = lane & 15, lq = lane >> 4;
  int kb = lq*8;
  unsigned nw = (unsigned)(nt*256 + w*64);         // wave n-base
  unsigned eb = (unsigned)(b*64) * NPIX;
  f32x4 acc[4][4];
  #pragma unroll
  for (int i=0;i<4;++i)
    #pragma unroll
    for (int j=0;j<4;++j) acc[i][j] = (f32x4){0.f,0.f,0.f,0.f};
  #pragma unroll
  for (int ks = 0; ks < 2; ++ks){
    // A-frags for this ks: W[c][d], c = mi*16+jc, d = ks*32+kb..+8  (L1/L2-hot)
    bf16x8 A[4];
    #pragma unroll
    for (int mi = 0; mi < 4; ++mi)
      A[mi] = *(const bf16x8*)&Wp[(mi*16 + jc)*64 + ks*32 + kb];
    unsigned rbase = eb + (unsigned)(ks*32 + kb) * NPIX;
    #pragma unroll
    for (int j = 0; j < 4; ++j){
      unsigned nn = nw + j*16 + jc;
      float f0 = E[rbase + 0*NPIX + nn];
      float f1 = E[rbase + 1*NPIX + nn];
      float f2 = E[rbase + 2*NPIX + nn];
      float f3 = E[rbase + 3*NPIX + nn];
      float f4v = E[rbase + 4*NPIX + nn];
      float f5 = E[rbase + 5*NPIX + nn];
      float f6 = E[rbase + 6*NPIX + nn];
      float f7 = E[rbase + 7*NPIX + nn];
      bf16x8 bv;
      bv[0]=(short)f2bf(f0); bv[1]=(short)f2bf(f1); bv[2]=(short)f2bf(f2); bv[3]=(short)f2bf(f3);
      bv[4]=(short)f2bf(f4v); bv[5]=(short)f2bf(f5); bv[6]=(short)f2bf(f6); bv[7]=(short)f2bf(f7);
      #pragma unroll
      for (int mi = 0; mi < 4; ++mi)
        acc[mi][j] = __builtin_amdgcn_mfma_f32_16x16x32_bf16(A[mi], bv, acc[mi][j], 0, 0, 0);
    }
  }
  float mean = meanA[t], mnt = mntA[t], inv = invA[t];
  long Mbase = (t & 1) ? O_M2 : O_M1;
  long g = t >> 1;
  #pragma unroll
  for (int mi = 0; mi < 4; ++mi){
    #pragma unroll
    for (int rr = 0; rr < 4; ++rr){
      int c = mi*16 + lq*4 + rr;
      unsigned fro = eb + (unsigned)c * NPIX;
      unsigned obase = (unsigned)(Mbase + ((long)(b*256 + g*64 + c))*NPIX);
      #pragma unroll
      for (int j = 0; j < 4; ++j){
        unsigned nn = nw + j*16 + jc;
        float f = E[fro + nn];
        float tv = fmaxf(f - mean, 1e-10f);
        float val = (tv - mnt)*inv + acc[mi][j][rr] + f;
        out[obase + nn] = val;
        out[obase + nn + (unsigned)FLATD] = val;
      }
    }
  }
}

// ---------------- activation outputs (reads am in-place from ViA region) ----------------
__global__ void k_acts(const unsigned* __restrict__ mmxa, float* __restrict__ out){
  long e = ((long)blockIdx.x*256 + threadIdx.x) * 4;
  float mn = fdec(mmxa[0]);
  float inv = 1.0f / (fdec(mmxa[1]) - mn + 1e-10f);
  f4 a = *(const f4*)&out[O_VIA + e];
  f4 nam = (a - mn) * inv;
  *(f4*)&out[O_IRA + e] = nam;
  *(f4*)&out[O_VIA + e] = 1.0f - nam;
}

extern "C" void kernel_launch(void* const* d_in, const int* in_sizes, int n_in,
                              void* d_out, int out_size, void* d_ws, size_t ws_size,
                              hipStream_t stream){
  (void)in_sizes; (void)n_in; (void)out_size; (void)ws_size;
  EPtrs ep;
  for (int i = 0; i < 8; ++i) ep.p[i] = (const float*)d_in[i];
  const float* fc = (const float*)d_in[8];
  const float* w1 = (const float*)d_in[9];
  const float* b1 = (const float*)d_in[10];
  const float* w2 = (const float*)d_in[11];
  const float* b2 = (const float*)d_in[12];
  float* out = (float*)d_out;
  char* ws = (char*)d_ws;
  float* sump   = (float*)(ws + WS_SUMP);
  unsigned* mmxe = (unsigned*)(ws + WS_MMXE);
  unsigned* mmxa = (unsigned*)(ws + WS_MMXA);
  float* meanA  = (float*)(ws + WS_MEAN);
  float* mntA   = (float*)(ws + WS_MNT);
  float* invA   = (float*)(ws + WS_INV);
  u16*   w1m    = (u16*)(ws + WS_W1M);
  // d_out-aliased scratch (each consumed before its real output is written):
  float* gram = out + O_M1F;            // consumed by k_softmax, overwritten by k_fuse
  float* cat  = out + O_M2F;            // consumed by k_conv2/k_maps, overwritten by k_fuse
  u16*   Wb   = (u16*)(out + O_IRA);    // consumed by k_fuse, overwritten by k_acts
  float* am   = out + O_VIA;            // consumed by k_maps/k_acts (in-place)

  k_prep      <<<288, 256, 0, stream>>>(w1, w1m, mmxe, mmxa);
  k_stats_gram<<<1024,256, 0, stream>>>(ep, gram, sump, mmxe);
  k_softmax   <<<32,  256, 0, stream>>>(gram, Wb, sump, mmxe, meanA, mntA, invA);
  k_conv1     <<<512, 512, 0, stream>>>(fc, w1m, b1, cat);
  k_conv2     <<<512, 256, 0, stream>>>(cat, w2, b2, am, mmxa);
  k_maps      <<<4096,256, 0, stream>>>(cat, am, mmxa, out);
  k_fuse      <<<2048,256, 0, stream>>>(ep, Wb, meanA, mntA, invA, out);
  k_acts      <<<64,  256, 0, stream>>>(mmxa, out);
}

// Round 4
// 245.424 us; speedup vs baseline: 1.7708x; 1.0047x over previous
//
#include <hip/hip_runtime.h>
#include <stdint.h>
#include <math.h>

typedef float f4 __attribute__((ext_vector_type(4)));
typedef float f32x4 __attribute__((ext_vector_type(4)));
typedef short bf16x8 __attribute__((ext_vector_type(8)));
typedef _Float16 f16x8 __attribute__((ext_vector_type(8)));
typedef unsigned short u16;
typedef unsigned short u16x4 __attribute__((ext_vector_type(4)));

#define NPIX 16384

// d_out offsets (floats). Return order: M1, M2, M1flat, M2flat, Ir_map, Vi_map, IrA, ViA
#define O_M1   0l
#define O_M2   16777216l
#define O_M1F  33554432l
#define O_M2F  50331648l
#define O_IR   67108864l
#define O_VI   71303168l
#define O_IRA  75497472l
#define O_VIA  75563008l
#define FLATD  33554432l   // offset from M to its flat duplicate (same for M1,M2)

// ws offsets (bytes)
#define WS_SUMP 0        // 1024 floats (8t * 4b * 32s)
#define WS_MMXE 4096     // 16 uints (per tensor min/max encoded)
#define WS_MMXA 4160     // 2 uints (activation map min/max)
#define WS_MEAN 4224     // 8 floats
#define WS_MNT  4256     // 8 floats
#define WS_INV  4288     // 8 floats
#define WS_W1M  8192     // 73728 u16, w1 as f16 relaid [icc][k9][oc][ic]

struct EPtrs { const float* p[8]; };

__device__ __forceinline__ u16 f2bf(float x){
  unsigned u = __float_as_uint(x);
  unsigned r = (u + 0x7fffu + ((u >> 16) & 1u)) >> 16;   // RNE
  return (u16)r;
}
__device__ __forceinline__ float bf2f(u16 v){
  return __uint_as_float(((unsigned)v) << 16);
}
__device__ __forceinline__ u16 f2h(float x){
  _Float16 h = (_Float16)x;
  u16 r; __builtin_memcpy(&r, &h, 2);
  return r;
}
// monotone float<->uint map for deterministic atomic min/max
__device__ __forceinline__ unsigned fenc(float x){
  unsigned u = __float_as_uint(x);
  return (u & 0x80000000u) ? ~u : (u | 0x80000000u);
}
__device__ __forceinline__ float fdec(unsigned u){
  unsigned v = (u & 0x80000000u) ? (u & 0x7fffffffu) : ~u;
  return __uint_as_float(v);
}

// ---------------- weight re-layout (+ atomic init in block 0) ----------------
__global__ void k_prep(const float* __restrict__ w1, u16* __restrict__ w1m,
                       unsigned* mmxe, unsigned* mmxa){
  if (blockIdx.x == 0 && threadIdx.x < 9){
    int t = threadIdx.x;
    if (t < 8){ mmxe[2*t] = 0xFFFFFFFFu; mmxe[2*t+1] = 0u; }
    else      { mmxa[0] = 0xFFFFFFFFu; mmxa[1] = 0u; }
  }
  int i = blockIdx.x*256 + threadIdx.x;
  if (i < 73728){
    int ic32 = i & 31;
    int oc   = (i >> 5) & 63;
    int k9   = (i >> 11) % 9;
    int icc  = i / 18432;
    float v = w1[(oc*128 + icc*32 + ic32)*9 + k9];
    w1m[i] = f2h(v);
  }
}

// ---------------- per-tensor stats + Gram partials (MFMA bf16) ----------------
// grid 1024 = 8 tensors * 4 batch * 32 slices(512 n each). block 256.
__global__ __launch_bounds__(256) void k_stats_gram(EPtrs eps,
    float* __restrict__ gram, float* __restrict__ sump, unsigned* __restrict__ mmxe){
  int bid = blockIdx.x;
  int t = bid >> 7; int rb = bid & 127; int b = rb >> 5; int s = rb & 31;
  const float* E = eps.p[t];
  __shared__ u16 lds[64*136];           // [c][n(128)+pad8] bf16
  __shared__ float red[768];
  int tid = threadIdx.x;
  int lane = tid & 63, wave = tid >> 6;
  f32x4 acc[4];
  #pragma unroll
  for (int i=0;i<4;++i) acc[i] = (f32x4){0.f,0.f,0.f,0.f};
  float vmin = 3.4e38f, vmax = -3.4e38f, vsum = 0.f;
  int rowS = tid >> 5;            // 0..7
  int colS = (tid & 31) * 4;      // 0..124
  int rA = wave*16 + (lane & 15);
  int kb = (lane >> 4) * 8;
  long nbase = (long)s * 512;
  for (int ch = 0; ch < 4; ++ch){
    long n0 = nbase + ch*128;
    __syncthreads();
    #pragma unroll
    for (int p = 0; p < 8; ++p){
      int row = p*8 + rowS;
      f4 v = *(const f4*)&E[(long)(b*64 + row)*NPIX + n0 + colS];
      vsum += v[0]+v[1]+v[2]+v[3];
      vmin = fminf(vmin, fminf(fminf(v[0],v[1]), fminf(v[2],v[3])));
      vmax = fmaxf(vmax, fmaxf(fmaxf(v[0],v[1]), fmaxf(v[2],v[3])));
      u16x4 w; w[0]=f2bf(v[0]); w[1]=f2bf(v[1]); w[2]=f2bf(v[2]); w[3]=f2bf(v[3]);
      *(u16x4*)&lds[row*136 + colS] = w;
    }
    __syncthreads();
    #pragma unroll
    for (int ks = 0; ks < 4; ++ks){
      bf16x8 a = *(bf16x8*)&lds[rA*136 + ks*32 + kb];
      #pragma unroll
      for (int cb = 0; cb < 4; ++cb){
        bf16x8 bb = *(bf16x8*)&lds[(cb*16 + (lane&15))*136 + ks*32 + kb];
        acc[cb] = __builtin_amdgcn_mfma_f32_16x16x32_bf16(a, bb, acc[cb], 0, 0, 0);
      }
    }
  }
  // gram partial write: S[c][d], c = 16*wave + 4*(lane>>4)+rr, d = 16*cb + (lane&15)
  long gbase = ((long)((t*4 + b)*32 + s)) * 4096;
  #pragma unroll
  for (int cb = 0; cb < 4; ++cb){
    int d = cb*16 + (lane & 15);
    #pragma unroll
    for (int rr = 0; rr < 4; ++rr){
      int c = 16*wave + 4*(lane>>4) + rr;
      gram[gbase + c*64 + d] = acc[cb][rr];
    }
  }
  // stats reduce
  red[tid] = vsum; red[256+tid] = vmin; red[512+tid] = vmax;
  __syncthreads();
  for (int off = 128; off > 0; off >>= 1){
    if (tid < off){
      red[tid] += red[tid+off];
      red[256+tid] = fminf(red[256+tid], red[256+tid+off]);
      red[512+tid] = fmaxf(red[512+tid], red[512+tid+off]);
    }
    __syncthreads();
  }
  if (tid == 0){
    sump[t*128 + b*32 + s] = red[0];
    atomicMin(&mmxe[2*t], fenc(red[256]));
    atomicMax(&mmxe[2*t+1], fenc(red[512]));
  }
}

// ---------------- reduce 32 gram slices -> gram2 (deterministic s-order) ----------------
// grid 256 = 32 (t,b) * 8 chunks(512 elems). block 256: thread handles 2 elems.
__global__ __launch_bounds__(256) void k_gramred(const float* __restrict__ gram,
                                                 float* __restrict__ gram2){
  int bid = blockIdx.x;
  int tb = bid >> 3, chunk = bid & 7;
  int e0 = chunk*512 + threadIdx.x;
  long gb = (long)tb * 32 * 4096;
  float a0 = 0.f, a1 = 0.f;
  #pragma unroll
  for (int s = 0; s < 32; ++s){
    a0 += gram[gb + s*4096 + e0];
    a1 += gram[gb + s*4096 + e0 + 256];
  }
  gram2[(long)tb*4096 + e0] = a0;
  gram2[(long)tb*4096 + e0 + 256] = a1;
}

// ---------------- softmax over axis=1 + per-tensor scalar finalize ----------------
// grid 32 = (t,b). W[c][d] bf16 written to Wb.
__global__ void k_softmax(const float* __restrict__ gram2, u16* __restrict__ Wb,
                          const float* __restrict__ sump, const unsigned* __restrict__ mmxe,
                          float* __restrict__ meanA, float* __restrict__ mntA, float* __restrict__ invA){
  int bid = blockIdx.x; int t = bid >> 2; int b = bid & 3;
  __shared__ float S[64*65];
  int tid = threadIdx.x;
  // fold finalize into b==0 block (used only by later k_fuse)
  if (b == 0 && tid == 0){
    float s = 0.f;
    for (int j = 0; j < 128; ++j) s += sump[t*128 + j];
    float mean = s / 4194304.0f;
    float mn = fdec(mmxe[2*t]), mx = fdec(mmxe[2*t+1]);
    float mnt = fmaxf(mn - mean, 1e-10f);
    float mxt = fmaxf(mx - mean, 1e-10f);
    meanA[t] = mean; mntA[t] = mnt;
    invA[t] = 1.0f / (mxt - mnt + 1e-10f);
  }
  long gb = (long)(t*4 + b)*4096;
  for (int i = tid; i < 4096; i += 256)
    S[(i>>6)*65 + (i&63)] = gram2[gb + i];
  __syncthreads();
  if (tid < 64){
    int d = tid;
    float mx = -3.4e38f;
    for (int c = 0; c < 64; ++c) mx = fmaxf(mx, S[c*65+d]);
    float sum = 0.f;
    for (int c = 0; c < 64; ++c){ float e = expf(S[c*65+d]-mx); S[c*65+d] = e; sum += e; }
    float inv = 1.0f/sum;
    long wb = (long)(t*4 + b)*4096;
    for (int c = 0; c < 64; ++c) Wb[wb + c*64 + d] = f2bf(S[c*65+d]*inv);
  }
}

// ---------------- conv1 3x3 implicit-GEMM MFMA f16 + bias + leaky ----------------
// grid 512 = (b,h) XCD-swizzled. block 512 = 8 waves: wave = (mg 2) x (ng 4).
__global__ __launch_bounds__(512) void k_conv1(const float* __restrict__ fc,
    const u16* __restrict__ w1m, const float* __restrict__ b1, float* __restrict__ cat){
  int bid = blockIdx.x;
  int vb = (bid & 7)*64 + (bid >> 3);      // XCD-chunked: contiguous h-bands per XCD
  int b = vb >> 7, h = vb & 127;
  __shared__ u16 xin[32*3*140];            // [ic32][r3][s140] f16 bits; s = w_in + 4
  int tid = threadIdx.x;
  int lane = tid & 63, wv = tid >> 6;
  int mg = wv >> 2, ng = wv & 3;
  int l15 = lane & 15, lq = lane >> 4;
  if (tid < 192){
    int ic = tid / 6, rem = tid % 6;
    int r = rem >> 1, sx = (rem & 1) ? 132 : 3;
    xin[(ic*3 + r)*140 + sx] = 0;
  }
  f32x4 acc[2][2];
  #pragma unroll
  for (int i=0;i<2;++i)
    #pragma unroll
    for (int j=0;j<2;++j) acc[i][j] = (f32x4){0.f,0.f,0.f,0.f};
  for (int icc = 0; icc < 4; ++icc){
    __syncthreads();
    #pragma unroll
    for (int it = 0; it < 6; ++it){
      int idx = tid + it*512;              // < 3072
      int ic = idx / 96, rem = idx % 96;
      int r = rem >> 5, q = rem & 31;
      int hr = h + r - 1;
      f4 v = (f4){0.f,0.f,0.f,0.f};
      if ((unsigned)hr < 128u)
        v = *(const f4*)&fc[(long)((b*128 + icc*32 + ic)*128 + hr)*128 + 4*q];
      u16x4 w; w[0]=f2h(v[0]); w[1]=f2h(v[1]); w[2]=f2h(v[2]); w[3]=f2h(v[3]);
      *(u16x4*)&xin[(ic*3 + r)*140 + 4 + 4*q] = w;
    }
    __syncthreads();
    #pragma unroll
    for (int kh = 0; kh < 3; ++kh){
      #pragma unroll
      for (int kw = 0; kw < 3; ++kw){
        int k9 = kh*3 + kw;
        f16x8 A[2];
        #pragma unroll
        for (int mi = 0; mi < 2; ++mi){
          int m = mg*2 + mi;
          A[mi] = *(const f16x8*)&w1m[(((icc*9 + k9)*64) + m*16 + l15)*32 + lq*8];
        }
        #pragma unroll
        for (int ji = 0; ji < 2; ++ji){
          int s = ng*32 + ji*16 + l15 + kw + 3;
          int kb = lq*8;
          f16x8 bv;
          #pragma unroll
          for (int e = 0; e < 8; ++e){
            u16 raw = xin[((kb + e)*3 + kh)*140 + s];
            _Float16 hh; __builtin_memcpy(&hh, &raw, 2);
            bv[e] = hh;
          }
          acc[0][ji] = __builtin_amdgcn_mfma_f32_16x16x32_f16(A[0], bv, acc[0][ji], 0, 0, 0);
          acc[1][ji] = __builtin_amdgcn_mfma_f32_16x16x32_f16(A[1], bv, acc[1][ji], 0, 0, 0);
        }
      }
    }
  }
  #pragma unroll
  for (int mi = 0; mi < 2; ++mi){
    #pragma unroll
    for (int rr = 0; rr < 4; ++rr){
      int oc = (mg*2 + mi)*16 + lq*4 + rr;
      float bb = b1[oc];
      #pragma unroll
      for (int ji = 0; ji < 2; ++ji){
        int w = ng*32 + ji*16 + l15;
        float v = acc[mi][ji][rr] + bb;
        v = v > 0.f ? v : 0.01f*v;
        cat[(long)((b*64 + oc)*128 + h)*128 + w] = v;
      }
    }
  }
}

// ---------------- conv2 3x3 (64ch -> 1) + bias, plus global min/max of result ----------------
// grid 512 = (b,h). block 256. LDS core at cl = w_in + 4 (8B-aligned staging).
__global__ __launch_bounds__(256) void k_conv2(const float* __restrict__ cat,
    const float* __restrict__ w2, const float* __restrict__ b2p,
    float* __restrict__ am, unsigned* __restrict__ mmxa){
  int bid = blockIdx.x; int b = bid >> 7; int h = bid & 127;
  __shared__ u16 l2[64*3*136];
  __shared__ float w2l[576];
  __shared__ float red2[256];
  int tid = threadIdx.x;
  for (int i = tid; i < 576; i += 256) w2l[i] = w2[i];
  if (tid < 192){
    int ic = tid / 3, r = tid % 3;
    l2[ic*408 + r*136 + 3]   = 0;   // w_in = -1
    l2[ic*408 + r*136 + 132] = 0;   // w_in = 128
  }
  #pragma unroll
  for (int rep = 0; rep < 3; ++rep){
    int idx = rep*256 + tid;             // < 768 = 64ic * 3r * 4q
    int ic = idx / 12; int rem = idx - ic*12; int r = rem >> 2; int q = rem & 3;
    int hr = h + r - 1;
    #pragma unroll
    for (int k = 0; k < 8; ++k){
      int w = q*32 + 4*k;
      f4 v = (f4){0.f,0.f,0.f,0.f};
      if ((unsigned)hr < 128u)
        v = *(const f4*)&cat[(long)((b*64 + ic)*128 + hr)*128 + w];
      u16x4 u; u[0]=f2bf(v[0]); u[1]=f2bf(v[1]); u[2]=f2bf(v[2]); u[3]=f2bf(v[3]);
      *(u16x4*)&l2[ic*408 + r*136 + 4 + w] = u;
    }
  }
  __syncthreads();
  int w = tid & 127, icg = tid >> 7;
  float a = 0.f;
  for (int ic = icg*32; ic < icg*32+32; ++ic){
    #pragma unroll
    for (int r = 0; r < 3; ++r)
      #pragma unroll
      for (int kw = 0; kw < 3; ++kw)
        a = fmaf(bf2f(l2[ic*408 + r*136 + (w + kw + 3)]), w2l[ic*9 + r*3 + kw], a);
  }
  red2[tid] = a;
  __syncthreads();
  float av = 0.f;
  if (icg == 0){
    av = red2[w] + red2[128 + w] + b2p[0];
    am[(long)(b*128 + h)*128 + w] = av;
  }
  __syncthreads();
  red2[tid] = (icg == 0) ? av : -3.4e38f;
  __syncthreads();
  for (int off = 128; off > 0; off >>= 1){
    if (tid < off) red2[tid] = fmaxf(red2[tid], red2[tid+off]);
    __syncthreads();
  }
  if (tid == 0) atomicMax(&mmxa[1], fenc(red2[0]));
  __syncthreads();
  red2[tid] = (icg == 0) ? av : 3.4e38f;
  __syncthreads();
  for (int off = 128; off > 0; off >>= 1){
    if (tid < off) red2[tid] = fminf(red2[tid], red2[tid+off]);
    __syncthreads();
  }
  if (tid == 0) atomicMin(&mmxa[0], fenc(red2[0]));
}

// ---------------- Ir/Vi maps ----------------
__global__ void k_maps(const float* __restrict__ cat, const float* __restrict__ am,
                       const unsigned* __restrict__ mmxa, float* __restrict__ out){
  long e = ((long)blockIdx.x*256 + threadIdx.x) * 4;
  float mn = fdec(mmxa[0]);
  float inv = 1.0f / (fdec(mmxa[1]) - mn + 1e-10f);
  f4 c = *(const f4*)&cat[e];
  f4 a = *(const f4*)&am[(e >> 20)*16384 + (e & 16383)];
  f4 nam = (a - mn) * inv;
  f4 ir = nam * c;
  f4 vi = (1.0f - nam) * c;
  *(f4*)&out[O_IR + e] = ir;
  *(f4*)&out[O_VI + e] = vi;
}

// ---------------- fuse: stage E tile in LDS (f32, swizzled), MFMA fw, epilogue ----------------
// grid 4096 = 8t * 4b * 128 nt(128 n). block 256 = 4 waves; wave w -> 32 n.
// LDS tile [n 128][c 64] f32; element (c,n) at float-idx n*64 + (((c>>2)^(n&15))<<2) + (c&3).
__global__ __launch_bounds__(256, 4) void k_fuse(EPtrs eps, const u16* __restrict__ Wb,
    const float* __restrict__ meanA, const float* __restrict__ mntA, const float* __restrict__ invA,
    float* __restrict__ out){
  int bid = blockIdx.x;
  int t = bid >> 9; int rem = bid & 511; int b = rem >> 7; int nt = rem & 127;
  const float* E = eps.p[t];
  const u16* Wp = Wb + (long)(t*4 + b)*4096;
  __shared__ float tileF[8192];       // 32 KB
  int tid = threadIdx.x; int lane = tid & 63; int w = tid >> 6;
  int jc = lane & 15, lq = lane >> 4;
  long n0 = (long)nt * 128;
  long eb = (long)(b*64) * NPIX;
  // A-frag prefetch: W[c][d], c = mi*16+jc, d = ks*32 + lq*8 .. +8 (L2-hot)
  bf16x8 A[2][4];
  #pragma unroll
  for (int ks = 0; ks < 2; ++ks)
    #pragma unroll
    for (int mi = 0; mi < 4; ++mi)
      A[ks][mi] = *(const bf16x8*)&Wp[(mi*16 + jc)*64 + ks*32 + lq*8];
  // stage E tile: 4 lane-groups, each iter stages rows c0..c0+3 over a 64-n half
  #pragma unroll
  for (int it = 0; it < 8; ++it){
    int a = it*4 + w;                  // 0..31
    int c0 = (a >> 1) << 2;
    int n = (a & 1)*64 + lane;
    long src = eb + (long)c0*NPIX + n0 + n;
    float f0 = E[src];
    float f1 = E[src + NPIX];
    float f2 = E[src + 2*NPIX];
    float f3 = E[src + 3*NPIX];
    f32x4 v = {f0, f1, f2, f3};
    *(f32x4*)&tileF[n*64 + (((c0 >> 2) ^ (n & 15)) << 2)] = v;
  }
  __syncthreads();
  f32x4 acc[4][2];
  #pragma unroll
  for (int i=0;i<4;++i)
    #pragma unroll
    for (int j=0;j<2;++j) acc[i][j] = (f32x4){0.f,0.f,0.f,0.f};
  int nw = w*32;
  #pragma unroll
  for (int ks = 0; ks < 2; ++ks){
    #pragma unroll
    for (int j = 0; j < 2; ++j){
      int n_t = nw + j*16 + jc;        // n_t & 15 == jc
      int p = ks*8 + lq*2;
      const float* base = &tileF[n_t*64];
      f32x4 q0 = *(const f32x4*)&base[(p ^ jc) << 2];
      f32x4 q1 = *(const f32x4*)&base[((p+1) ^ jc) << 2];
      bf16x8 bv;
      bv[0]=(short)f2bf(q0[0]); bv[1]=(short)f2bf(q0[1]);
      bv[2]=(short)f2bf(q0[2]); bv[3]=(short)f2bf(q0[3]);
      bv[4]=(short)f2bf(q1[0]); bv[5]=(short)f2bf(q1[1]);
      bv[6]=(short)f2bf(q1[2]); bv[7]=(short)f2bf(q1[3]);
      #pragma unroll
      for (int mi = 0; mi < 4; ++mi)
        acc[mi][j] = __builtin_amdgcn_mfma_f32_16x16x32_bf16(A[ks][mi], bv, acc[mi][j], 0, 0, 0);
    }
  }
  float mean = meanA[t], mnt = mntA[t], inv = invA[t];
  long Mbase = (t & 1) ? O_M2 : O_M1;
  long gr = t >> 1;
  #pragma unroll
  for (int mi = 0; mi < 4; ++mi){
    #pragma unroll
    for (int j = 0; j < 2; ++j){
      int n_t = nw + j*16 + jc;
      f32x4 fv = *(const f32x4*)&tileF[n_t*64 + (((mi*4 + lq) ^ jc) << 2)];
      #pragma unroll
      for (int rr = 0; rr < 4; ++rr){
        int c = mi*16 + lq*4 + rr;
        float f = fv[rr];
        float tv = fmaxf(f - mean, 1e-10f);
        float val = (tv - mnt)*inv + acc[mi][j][rr] + f;
        long dst = Mbase + ((long)(b*256 + gr*64 + c))*NPIX + n0 + n_t;
        out[dst] = val;
        out[dst + FLATD] = val;
      }
    }
  }
}

// ---------------- activation outputs (reads am in-place from ViA region) ----------------
__global__ void k_acts(const unsigned* __restrict__ mmxa, float* __restrict__ out){
  long e = ((long)blockIdx.x*256 + threadIdx.x) * 4;
  float mn = fdec(mmxa[0]);
  float inv = 1.0f / (fdec(mmxa[1]) - mn + 1e-10f);
  f4 a = *(const f4*)&out[O_VIA + e];
  f4 nam = (a - mn) * inv;
  *(f4*)&out[O_IRA + e] = nam;
  *(f4*)&out[O_VIA + e] = 1.0f - nam;
}

extern "C" void kernel_launch(void* const* d_in, const int* in_sizes, int n_in,
                              void* d_out, int out_size, void* d_ws, size_t ws_size,
                              hipStream_t stream){
  (void)in_sizes; (void)n_in; (void)out_size; (void)ws_size;
  EPtrs ep;
  for (int i = 0; i < 8; ++i) ep.p[i] = (const float*)d_in[i];
  const float* fc = (const float*)d_in[8];
  const float* w1 = (const float*)d_in[9];
  const float* b1 = (const float*)d_in[10];
  const float* w2 = (const float*)d_in[11];
  const float* b2 = (const float*)d_in[12];
  float* out = (float*)d_out;
  char* ws = (char*)d_ws;
  float* sump   = (float*)(ws + WS_SUMP);
  unsigned* mmxe = (unsigned*)(ws + WS_MMXE);
  unsigned* mmxa = (unsigned*)(ws + WS_MMXA);
  float* meanA  = (float*)(ws + WS_MEAN);
  float* mntA   = (float*)(ws + WS_MNT);
  float* invA   = (float*)(ws + WS_INV);
  u16*   w1m    = (u16*)(ws + WS_W1M);
  // d_out-aliased scratch (each consumed before its real output is written):
  float* gram  = out + O_M1F;           // partials; consumed by k_gramred, overwritten by k_fuse
  float* gram2 = out + O_IR;            // reduced;  consumed by k_softmax, overwritten by k_maps
  float* cat   = out + O_M2F;           // consumed by k_conv2/k_maps, overwritten by k_fuse
  u16*   Wb    = (u16*)(out + O_IRA);   // consumed by k_fuse, overwritten by k_acts
  float* am    = out + O_VIA;           // consumed by k_maps/k_acts (in-place)

  k_prep      <<<288, 256, 0, stream>>>(w1, w1m, mmxe, mmxa);
  k_stats_gram<<<1024,256, 0, stream>>>(ep, gram, sump, mmxe);
  k_gramred   <<<256, 256, 0, stream>>>(gram, gram2);
  k_softmax   <<<32,  256, 0, stream>>>(gram2, Wb, sump, mmxe, meanA, mntA, invA);
  k_conv1     <<<512, 512, 0, stream>>>(fc, w1m, b1, cat);
  k_conv2     <<<512, 256, 0, stream>>>(cat, w2, b2, am, mmxa);
  k_maps      <<<4096,256, 0, stream>>>(cat, am, mmxa, out);
  k_fuse      <<<4096,256, 0, stream>>>(ep, Wb, meanA, mntA, invA, out);
  k_acts      <<<64,  256, 0, stream>>>(mmxa, out);
}